// Round 7
// baseline (79.591 us; speedup 1.0000x reference)
//
#include <hip/hip_runtime.h>
#include <hip/hip_bf16.h>
#include <cstdint>

// VQ-VAE vector quantize: N=65536 vectors, D=64, K=512 codes.
// d_in[0]: inputs fp32 [65536,64], d_in[1]: embeddings fp32 [512,64]
// d_out: [0]=loss, [1..4194304]=latent (gathered fp32 embeddings)
//
// R7: max-occupancy main kernel. 16 KB single-buffered codebook passes,
// launch_bounds(256,8) -> 8 blocks = 32 waves/CU. Loss finished by the
// last block (agent-scope, deterministic order). 2 kernels total.

typedef __attribute__((ext_vector_type(8))) short bf16x8;
typedef __attribute__((ext_vector_type(4))) float f32x4;

__device__ __forceinline__ short f2bf(float f) {
    uint32_t u = __builtin_bit_cast(uint32_t, f);
    u += 0x7FFFu + ((u >> 16) & 1u);   // round-to-nearest-even
    return (short)(u >> 16);
}

// ws layout (bytes):
//  [0, 65536)     : B fragments bf16(-e), [ct(32)][ks(2)][lane(64)] x 16B
//  [65536, 67584) : ee_t[512] fp32 = 0.5*||e_k||^2, TRANSPOSED [cb(16)][ct(32)]
//  [67584, 71680) : partials[1024] fp32
//  [71680, 71684) : completion counter
#define WS_EE   65536
#define WS_PART 67584
#define WS_CTR  71680

// ---------------- Kernel 1: setup (8 blocks x 256) ----------------
__global__ __launch_bounds__(256)
void vq_setup(const float* __restrict__ emb, char* __restrict__ ws) {
    const int tid = threadIdx.x, bid = blockIdx.x;
    bf16x8* bfrag = (bf16x8*)ws;
    float* eet = (float*)(ws + WS_EE);
    if (bid == 0 && tid == 0) *(uint32_t*)(ws + WS_CTR) = 0u;
    #pragma unroll
    for (int k = 0; k < 2; ++k) {
        const int s = bid * 512 + k * 256 + tid;
        const int ct = s >> 7, ks = (s >> 6) & 1, ln = s & 63;
        const int code = (ct << 4) | (ln & 15);
        const int d0 = ks * 32 + ((ln >> 4) << 3);
        const float* src = emb + code * 64 + d0;
        float4 v0 = *(const float4*)src;
        float4 v1 = *(const float4*)(src + 4);
        bf16x8 b;
        b[0] = f2bf(-v0.x); b[1] = f2bf(-v0.y); b[2] = f2bf(-v0.z); b[3] = f2bf(-v0.w);
        b[4] = f2bf(-v1.x); b[5] = f2bf(-v1.y); b[6] = f2bf(-v1.z); b[7] = f2bf(-v1.w);
        bfrag[s] = b;
    }
    if (tid < 64) {
        const int c = bid * 64 + tid;            // code id
        const float4* e4 = (const float4*)(emb + c * 64);
        float s = 0.f;
        #pragma unroll
        for (int q = 0; q < 16; ++q) {
            float4 v = e4[q];
            s = fmaf(v.x, v.x, fmaf(v.y, v.y, fmaf(v.z, v.z, fmaf(v.w, v.w, s))));
        }
        eet[(c & 15) * 32 + (c >> 4)] = 0.5f * s;   // transposed, pre-halved
    }
}

// ---------------- Kernel 2: main (1024 blocks x 256, 8 blocks/CU) ----------------
// Wave owns 16 rows (1 M-tile). Codebook in 4 single-buffered 16 KB passes.
__global__ __launch_bounds__(256, 8)
void vq_main(const float* __restrict__ flat, const float* __restrict__ emb,
             char* __restrict__ ws, float* __restrict__ out) {
    __shared__ bf16x8 lbuf[1024];   // 16 KB pass buffer
    __shared__ float red[4];
    __shared__ int lastflag;

    const int tid = threadIdx.x, bid = blockIdx.x;
    const int lane = tid & 63, wid = tid >> 6;
    const int cb = lane & 15;
    const int rb = bid * 64 + wid * 16;   // wave's 16 rows
    const char* wsg = (const char*)ws;

    // ---- A loads: 1 M-tile x 2 k-steps x 2 float4 ----
    const float* asrc = flat + (long)(rb + cb) * 64 + ((lane >> 4) << 3);
    float4 ar[2][2];
    ar[0][0] = *(const float4*)asrc;
    ar[0][1] = *(const float4*)(asrc + 4);
    ar[1][0] = *(const float4*)(asrc + 32);
    ar[1][1] = *(const float4*)(asrc + 36);

    // ---- issue pass-0 staging (16 KB, global_load_lds width 16, linear) ----
    {
        char* dst = (char*)lbuf;
        #pragma unroll
        for (int k = 0; k < 4; ++k) {
            const int off = (k * 256 + tid) * 16;
            __builtin_amdgcn_global_load_lds(
                (const __attribute__((address_space(1))) void*)(wsg + off),
                (__attribute__((address_space(3))) void*)(dst + off), 16, 0, 0);
        }
    }

    // ---- fp32 ||x||^2 partial + bf16 convert (overlaps staging) ----
    float xx = 0.f;
    #pragma unroll
    for (int ks = 0; ks < 2; ++ks)
        #pragma unroll
        for (int u = 0; u < 2; ++u) {
            float4 v = ar[ks][u];
            xx = fmaf(v.x, v.x, fmaf(v.y, v.y, fmaf(v.z, v.z, fmaf(v.w, v.w, xx))));
        }
    bf16x8 a[2];
    #pragma unroll
    for (int ks = 0; ks < 2; ++ks) {
        float4 v0 = ar[ks][0], v1 = ar[ks][1];
        bf16x8 f;
        f[0] = f2bf(v0.x); f[1] = f2bf(v0.y); f[2] = f2bf(v0.z); f[3] = f2bf(v0.w);
        f[4] = f2bf(v1.x); f[5] = f2bf(v1.y); f[6] = f2bf(v1.z); f[7] = f2bf(v1.w);
        a[ks] = f;
    }

    // ---- main loop: 4 passes x 8 col-tiles, single-buffered ----
    float pm[4];
    #pragma unroll
    for (int i = 0; i < 4; ++i) pm[i] = __builtin_bit_cast(float, 0x7F800000u);

    #pragma unroll
    for (int p = 0; p < 4; ++p) {
        if (p) {
            __syncthreads();   // previous pass fully consumed
            char* dst = (char*)lbuf;
            const int gbase = p * 16384;
            #pragma unroll
            for (int k = 0; k < 4; ++k) {
                const int off = (k * 256 + tid) * 16;
                __builtin_amdgcn_global_load_lds(
                    (const __attribute__((address_space(1))) void*)(wsg + gbase + off),
                    (__attribute__((address_space(3))) void*)(dst + off), 16, 0, 0);
            }
        }
        // this pass's 8 half-norm values for this lane's column class (L1-hit)
        const float4* hp = (const float4*)(wsg + WS_EE + cb * 128 + p * 32);
        float4 h0 = hp[0], h1 = hp[1];
        __syncthreads();       // staging complete (vmcnt(0) at barrier)

        #pragma unroll
        for (int ctl = 0; ctl < 8; ++ctl) {
            bf16x8 b0 = lbuf[ctl * 128 + lane];
            bf16x8 b1 = lbuf[ctl * 128 + 64 + lane];
            const int ct = p * 8 + ctl;
            const int colv = (ct << 4) | cb;
            const float h = (ctl < 4) ? ((ctl == 0) ? h0.x : (ctl == 1) ? h0.y : (ctl == 2) ? h0.z : h0.w)
                                      : ((ctl == 4) ? h1.x : (ctl == 5) ? h1.y : (ctl == 6) ? h1.z : h1.w);
            f32x4 acc = {h, h, h, h};        // 0.5||e||^2 - x.e   (B = -e)
            acc = __builtin_amdgcn_mfma_f32_16x16x32_bf16(a[0], b0, acc, 0, 0, 0);
            acc = __builtin_amdgcn_mfma_f32_16x16x32_bf16(a[1], b1, acc, 0, 0, 0);
            #pragma unroll
            for (int j = 0; j < 4; ++j) {
                uint32_t dp = (__builtin_bit_cast(uint32_t, acc[j]) & 0xFFFFFE00u) | (uint32_t)colv;
                pm[j] = fminf(pm[j], __builtin_bit_cast(float, dp));
            }
        }
    }

    // ---- butterfly min over the 16 column-class lanes ----
    #pragma unroll
    for (int m = 1; m < 16; m <<= 1) {
        #pragma unroll
        for (int i = 0; i < 4; ++i)
            pm[i] = fminf(pm[i], __shfl_xor(pm[i], m, 64));
    }

    // ---- loss partial: sum_rows( ||x||^2 + 2*unpack(pm_min) ) ----
    float t = xx;
    if (cb == 0) {
        #pragma unroll
        for (int j = 0; j < 4; ++j) {
            float v = __builtin_bit_cast(float, __builtin_bit_cast(uint32_t, pm[j]) & 0xFFFFFE00u);
            t = fmaf(2.f, v, t);
        }
    }
    #pragma unroll
    for (int m = 32; m; m >>= 1) t += __shfl_down(t, m, 64);
    if (lane == 0) red[wid] = t;

    // ---- epilogue: per-row code broadcast + gather + coalesced latent store ----
    float* ob = out + 1 + (long)rb * 64;
    #pragma unroll 4
    for (int r = 0; r < 16; ++r) {
        float v = __shfl(pm[r & 3], (r >> 2) << 4, 64);
        const int ix = (int)(__builtin_bit_cast(uint32_t, v) & 0x1FFu);
        ob[r * 64 + lane] = emb[ix * 64 + lane];
    }

    // ---- last-block loss finish (agent-scope, deterministic sum order) ----
    __syncthreads();
    float* part = (float*)(ws + WS_PART);
    if (tid == 0) {
        float s = red[0] + red[1] + red[2] + red[3];
        __hip_atomic_store(part + bid, s, __ATOMIC_RELEASE, __HIP_MEMORY_SCOPE_AGENT);
        uint32_t old = __hip_atomic_fetch_add((uint32_t*)(ws + WS_CTR), 1u,
                                              __ATOMIC_ACQ_REL, __HIP_MEMORY_SCOPE_AGENT);
        lastflag = (old == 1023u);
    }
    __syncthreads();
    if (lastflag && wid == 0) {
        float acc = 0.f;
        #pragma unroll
        for (int i = 0; i < 16; ++i)
            acc += __hip_atomic_load(part + i * 64 + lane, __ATOMIC_ACQUIRE,
                                     __HIP_MEMORY_SCOPE_AGENT);
        #pragma unroll
        for (int m = 32; m; m >>= 1) acc += __shfl_down(acc, m, 64);
        // loss = 0.25*e_loss + q_loss = 1.25 * mse (forward)
        if (lane == 0) out[0] = 1.25f * acc / 4194304.0f;
    }
}

extern "C" void kernel_launch(void* const* d_in, const int* in_sizes, int n_in,
                              void* d_out, int out_size, void* d_ws, size_t ws_size,
                              hipStream_t stream) {
    const float* flat = (const float*)d_in[0];   // [65536,64]
    const float* emb  = (const float*)d_in[1];   // [512,64]
    float* out = (float*)d_out;
    char* ws = (char*)d_ws;

    vq_setup<<<8, 256, 0, stream>>>(emb, ws);
    vq_main<<<1024, 256, 0, stream>>>(flat, emb, ws, out);
}

// Round 8
// 78.876 us; speedup vs baseline: 1.0091x; 1.0091x over previous
//
#include <hip/hip_runtime.h>
#include <hip/hip_bf16.h>
#include <cstdint>

// VQ-VAE vector quantize: N=65536 vectors, D=64, K=512 codes.
// d_in[0]: inputs fp32 [65536,64], d_in[1]: embeddings fp32 [512,64]
// d_out: [0]=loss, [1..4194304]=latent (gathered fp32 embeddings)
//
// R8: R4 main-loop structure (best known: launch_bounds(256,4), 32KB single
// buffer, 2 codebook passes) + wide setup (16 blocks), last-block loss finish
// (no 3rd kernel), group-parallel shuffle-free epilogue.

typedef __attribute__((ext_vector_type(8))) short bf16x8;
typedef __attribute__((ext_vector_type(4))) float f32x4;

__device__ __forceinline__ short f2bf(float f) {
    uint32_t u = __builtin_bit_cast(uint32_t, f);
    u += 0x7FFFu + ((u >> 16) & 1u);   // round-to-nearest-even
    return (short)(u >> 16);
}

// ws layout (bytes):
//  [0, 65536)     : B fragments bf16(-e), [ct(32)][ks(2)][lane(64)] x 16B
//  [65536, 67584) : ee_t[512] fp32 = 0.5*||e_k||^2, TRANSPOSED [cb(16)][ct(32)]
//  [67584, 71680) : partials[1024] fp32
//  [71680, 71684) : completion counter
#define WS_EE   65536
#define WS_PART 67584
#define WS_CTR  71680

// ---------------- Kernel 1: setup (16 blocks x 256) ----------------
__global__ __launch_bounds__(256)
void vq_setup(const float* __restrict__ emb, char* __restrict__ ws) {
    const int tid = threadIdx.x, bid = blockIdx.x;
    bf16x8* bfrag = (bf16x8*)ws;
    float* eet = (float*)(ws + WS_EE);
    if (bid == 0 && tid == 0) *(uint32_t*)(ws + WS_CTR) = 0u;

    // one fragment slot per thread
    const int s = bid * 256 + tid;
    const int ct = s >> 7, ks = (s >> 6) & 1, ln = s & 63;
    const int code = (ct << 4) | (ln & 15);
    const int d0 = ks * 32 + ((ln >> 4) << 3);
    const float* src = emb + code * 64 + d0;
    float4 v0 = *(const float4*)src;
    float4 v1 = *(const float4*)(src + 4);
    bf16x8 b;
    b[0] = f2bf(-v0.x); b[1] = f2bf(-v0.y); b[2] = f2bf(-v0.z); b[3] = f2bf(-v0.w);
    b[4] = f2bf(-v1.x); b[5] = f2bf(-v1.y); b[6] = f2bf(-v1.z); b[7] = f2bf(-v1.w);
    bfrag[s] = b;

    // 32 norm codes per block
    if (tid < 32) {
        const int c = bid * 32 + tid;
        const float4* e4 = (const float4*)(emb + c * 64);
        float acc = 0.f;
        #pragma unroll
        for (int q = 0; q < 16; ++q) {
            float4 v = e4[q];
            acc = fmaf(v.x, v.x, fmaf(v.y, v.y, fmaf(v.z, v.z, fmaf(v.w, v.w, acc))));
        }
        eet[(c & 15) * 32 + (c >> 4)] = 0.5f * acc;   // transposed, pre-halved
    }
}

// ---------------- Kernel 2: main (1024 blocks x 256, 4 blocks/CU) ----------------
// Wave owns 16 rows (1 M-tile). Codebook in 2 passes through one 32 KB buffer.
__global__ __launch_bounds__(256, 4)
void vq_main(const float* __restrict__ flat, const float* __restrict__ emb,
             char* __restrict__ ws, float* __restrict__ out) {
    __shared__ bf16x8 lbuf[2048];   // 32 KB pass buffer
    __shared__ float red[4];
    __shared__ int lastflag;

    const int tid = threadIdx.x, bid = blockIdx.x;
    const int lane = tid & 63, wid = tid >> 6;
    const int cb = lane & 15, g = lane >> 4;
    const int rb = bid * 64 + wid * 16;   // wave's 16 rows
    const char* wsg = (const char*)ws;

    // ---- A loads: 1 M-tile x 2 k-steps x 2 float4 ----
    const float* asrc = flat + (long)(rb + cb) * 64 + (g << 3);
    float4 ar[2][2];
    ar[0][0] = *(const float4*)asrc;
    ar[0][1] = *(const float4*)(asrc + 4);
    ar[1][0] = *(const float4*)(asrc + 32);
    ar[1][1] = *(const float4*)(asrc + 36);

    // ---- issue pass-0 staging (32 KB, global_load_lds width 16, linear) ----
    {
        char* dst = (char*)lbuf;
        #pragma unroll
        for (int k = 0; k < 8; ++k) {
            const int off = (k * 256 + tid) * 16;
            __builtin_amdgcn_global_load_lds(
                (const __attribute__((address_space(1))) void*)(wsg + off),
                (__attribute__((address_space(3))) void*)(dst + off), 16, 0, 0);
        }
    }

    // ---- fp32 ||x||^2 partial + bf16 convert (overlaps staging) ----
    float xx = 0.f;
    #pragma unroll
    for (int ks = 0; ks < 2; ++ks)
        #pragma unroll
        for (int u = 0; u < 2; ++u) {
            float4 v = ar[ks][u];
            xx = fmaf(v.x, v.x, fmaf(v.y, v.y, fmaf(v.z, v.z, fmaf(v.w, v.w, xx))));
        }
    bf16x8 a[2];
    #pragma unroll
    for (int ks = 0; ks < 2; ++ks) {
        float4 v0 = ar[ks][0], v1 = ar[ks][1];
        bf16x8 f;
        f[0] = f2bf(v0.x); f[1] = f2bf(v0.y); f[2] = f2bf(v0.z); f[3] = f2bf(v0.w);
        f[4] = f2bf(v1.x); f[5] = f2bf(v1.y); f[6] = f2bf(v1.z); f[7] = f2bf(v1.w);
        a[ks] = f;
    }

    // ---- main loop: 2 passes x 16 col-tiles ----
    float pm[4];
    #pragma unroll
    for (int i = 0; i < 4; ++i) pm[i] = __builtin_bit_cast(float, 0x7F800000u);

    #pragma unroll
    for (int p = 0; p < 2; ++p) {
        if (p) {
            __syncthreads();   // previous pass fully consumed
            char* dst = (char*)lbuf;
            #pragma unroll
            for (int k = 0; k < 8; ++k) {
                const int off = (k * 256 + tid) * 16;
                __builtin_amdgcn_global_load_lds(
                    (const __attribute__((address_space(1))) void*)(wsg + 32768 + off),
                    (__attribute__((address_space(3))) void*)(dst + off), 16, 0, 0);
            }
        }
        // this pass's 16 half-norms for this lane's column class (L1-hit, fp32)
        const float4* hp = (const float4*)(wsg + WS_EE + cb * 128 + p * 64);
        float4 h0 = hp[0], h1 = hp[1], h2 = hp[2], h3 = hp[3];
        __syncthreads();       // staging complete (vmcnt(0) at barrier)

        #pragma unroll
        for (int ctl = 0; ctl < 16; ++ctl) {
            bf16x8 b0 = lbuf[ctl * 128 + lane];
            bf16x8 b1 = lbuf[ctl * 128 + 64 + lane];
            const int ct = p * 16 + ctl;
            const int colv = (ct << 4) | cb;
            const float4 hq = (ctl < 8) ? ((ctl < 4) ? h0 : h1) : ((ctl < 12) ? h2 : h3);
            const float h = (ctl & 3) == 0 ? hq.x : (ctl & 3) == 1 ? hq.y
                          : (ctl & 3) == 2 ? hq.z : hq.w;
            f32x4 acc = {h, h, h, h};        // 0.5||e||^2 - x.e   (B = -e)
            acc = __builtin_amdgcn_mfma_f32_16x16x32_bf16(a[0], b0, acc, 0, 0, 0);
            acc = __builtin_amdgcn_mfma_f32_16x16x32_bf16(a[1], b1, acc, 0, 0, 0);
            #pragma unroll
            for (int j = 0; j < 4; ++j) {
                uint32_t dp = (__builtin_bit_cast(uint32_t, acc[j]) & 0xFFFFFE00u) | (uint32_t)colv;
                pm[j] = fminf(pm[j], __builtin_bit_cast(float, dp));
            }
        }
    }

    // ---- butterfly min over the 16 column-class lanes ----
    #pragma unroll
    for (int m = 1; m < 16; m <<= 1) {
        #pragma unroll
        for (int i = 0; i < 4; ++i)
            pm[i] = fminf(pm[i], __shfl_xor(pm[i], m, 64));
    }
    // post-butterfly: group g's 16 lanes all hold winners of rows rb+g*4+j

    // ---- loss partial: sum_rows( ||x||^2 + 2*unpack(pm_min) ) ----
    float t = xx;
    if (cb == 0) {
        #pragma unroll
        for (int j = 0; j < 4; ++j) {
            float v = __builtin_bit_cast(float, __builtin_bit_cast(uint32_t, pm[j]) & 0xFFFFFE00u);
            t = fmaf(2.f, v, t);
        }
    }
    #pragma unroll
    for (int m = 32; m; m >>= 1) t += __shfl_down(t, m, 64);
    if (lane == 0) red[wid] = t;

    // ---- epilogue: shuffle-free group-parallel gather + store ----
    // group g owns rows rb+g*4+j; its 16 lanes cover the 64-dim row as float4s
    float* ob = out + 1 + (long)rb * 64;
    const int l4 = cb * 4;
    #pragma unroll
    for (int j = 0; j < 4; ++j) {
        const int ix = (int)(__builtin_bit_cast(uint32_t, pm[j]) & 0x1FFu);
        float4 e = *(const float4*)(emb + ix * 64 + l4);
        const int ro = (g * 4 + j) * 64 + l4;
        ob[ro] = e.x; ob[ro + 1] = e.y; ob[ro + 2] = e.z; ob[ro + 3] = e.w;
    }

    // ---- last-block loss finish (agent-scope, deterministic sum order) ----
    __syncthreads();
    float* part = (float*)(ws + WS_PART);
    if (tid == 0) {
        float s = red[0] + red[1] + red[2] + red[3];
        __hip_atomic_store(part + bid, s, __ATOMIC_RELEASE, __HIP_MEMORY_SCOPE_AGENT);
        uint32_t old = __hip_atomic_fetch_add((uint32_t*)(ws + WS_CTR), 1u,
                                              __ATOMIC_ACQ_REL, __HIP_MEMORY_SCOPE_AGENT);
        lastflag = (old == 1023u);
    }
    __syncthreads();
    if (lastflag && wid == 0) {
        float acc = 0.f;
        #pragma unroll
        for (int i = 0; i < 16; ++i)
            acc += __hip_atomic_load(part + i * 64 + lane, __ATOMIC_ACQUIRE,
                                     __HIP_MEMORY_SCOPE_AGENT);
        #pragma unroll
        for (int m = 32; m; m >>= 1) acc += __shfl_down(acc, m, 64);
        // loss = 0.25*e_loss + q_loss = 1.25 * mse (forward)
        if (lane == 0) out[0] = 1.25f * acc / 4194304.0f;
    }
}

extern "C" void kernel_launch(void* const* d_in, const int* in_sizes, int n_in,
                              void* d_out, int out_size, void* d_ws, size_t ws_size,
                              hipStream_t stream) {
    const float* flat = (const float*)d_in[0];   // [65536,64]
    const float* emb  = (const float*)d_in[1];   // [512,64]
    float* out = (float*)d_out;
    char* ws = (char*)d_ws;

    vq_setup<<<16, 256, 0, stream>>>(emb, ws);
    vq_main<<<1024, 256, 0, stream>>>(flat, emb, ws, out);
}

// Round 9
// 24.998 us; speedup vs baseline: 3.1839x; 3.1553x over previous
//
#include <hip/hip_runtime.h>
#include <hip/hip_bf16.h>
#include <cstdint>

// VQ-VAE vector quantize: N=65536 vectors, D=64, K=512 codes.
// d_in[0]: inputs fp32 [65536,64], d_in[1]: embeddings fp32 [512,64]
// d_out: [0]=loss, [1..4194304]=latent (gathered fp32 embeddings)
//
// R9: revert to R4 structure (best measured: 25.1 us). NO device-scope
// atomics (R7/R8 showed agent-scope release/acquire costs ~55 us via L2
// writeback per block). Wide setup (16 blocks), float4 shuffle-free
// epilogue, separate 1-block loss reduce.

typedef __attribute__((ext_vector_type(8))) short bf16x8;
typedef __attribute__((ext_vector_type(4))) float f32x4;

__device__ __forceinline__ short f2bf(float f) {
    uint32_t u = __builtin_bit_cast(uint32_t, f);
    u += 0x7FFFu + ((u >> 16) & 1u);   // round-to-nearest-even
    return (short)(u >> 16);
}

// ws layout (bytes):
//  [0, 65536)     : B fragments bf16(-e), [ct(32)][ks(2)][lane(64)] x 16B
//  [65536, 67584) : ee_t[512] fp32 = 0.5*||e_k||^2, TRANSPOSED [cb(16)][ct(32)]
//  [67584, 71680) : partials[1024] fp32
#define WS_EE   65536
#define WS_PART 67584

// ---------------- Kernel 1: setup (16 blocks x 256) ----------------
__global__ __launch_bounds__(256)
void vq_setup(const float* __restrict__ emb, char* __restrict__ ws) {
    const int tid = threadIdx.x, bid = blockIdx.x;
    bf16x8* bfrag = (bf16x8*)ws;
    float* eet = (float*)(ws + WS_EE);

    // one fragment slot per thread (16*256 = 4096 slots)
    const int s = bid * 256 + tid;
    const int ct = s >> 7, ks = (s >> 6) & 1, ln = s & 63;
    const int code = (ct << 4) | (ln & 15);
    const int d0 = ks * 32 + ((ln >> 4) << 3);
    const float* src = emb + code * 64 + d0;
    float4 v0 = *(const float4*)src;
    float4 v1 = *(const float4*)(src + 4);
    bf16x8 b;
    b[0] = f2bf(-v0.x); b[1] = f2bf(-v0.y); b[2] = f2bf(-v0.z); b[3] = f2bf(-v0.w);
    b[4] = f2bf(-v1.x); b[5] = f2bf(-v1.y); b[6] = f2bf(-v1.z); b[7] = f2bf(-v1.w);
    bfrag[s] = b;

    // 32 norm codes per block
    if (tid < 32) {
        const int c = bid * 32 + tid;
        const float4* e4 = (const float4*)(emb + c * 64);
        float acc = 0.f;
        #pragma unroll
        for (int q = 0; q < 16; ++q) {
            float4 v = e4[q];
            acc = fmaf(v.x, v.x, fmaf(v.y, v.y, fmaf(v.z, v.z, fmaf(v.w, v.w, acc))));
        }
        eet[(c & 15) * 32 + (c >> 4)] = 0.5f * acc;   // transposed, pre-halved
    }
}

// ---------------- Kernel 2: main (1024 blocks x 256, 4 blocks/CU) ----------------
// Wave owns 16 rows (1 M-tile). Codebook in 2 passes through one 32 KB buffer.
__global__ __launch_bounds__(256, 4)
void vq_main(const float* __restrict__ flat, const float* __restrict__ emb,
             char* __restrict__ ws, float* __restrict__ out) {
    __shared__ bf16x8 lbuf[2048];   // 32 KB pass buffer
    __shared__ float red[4];

    const int tid = threadIdx.x, bid = blockIdx.x;
    const int lane = tid & 63, wid = tid >> 6;
    const int cb = lane & 15, g = lane >> 4;
    const int rb = bid * 64 + wid * 16;   // wave's 16 rows
    const char* wsg = (const char*)ws;

    // ---- A loads: 1 M-tile x 2 k-steps x 2 float4 ----
    const float* asrc = flat + (long)(rb + cb) * 64 + (g << 3);
    float4 ar[2][2];
    ar[0][0] = *(const float4*)asrc;
    ar[0][1] = *(const float4*)(asrc + 4);
    ar[1][0] = *(const float4*)(asrc + 32);
    ar[1][1] = *(const float4*)(asrc + 36);

    // ---- issue pass-0 staging (32 KB, global_load_lds width 16, linear) ----
    {
        char* dst = (char*)lbuf;
        #pragma unroll
        for (int k = 0; k < 8; ++k) {
            const int off = (k * 256 + tid) * 16;
            __builtin_amdgcn_global_load_lds(
                (const __attribute__((address_space(1))) void*)(wsg + off),
                (__attribute__((address_space(3))) void*)(dst + off), 16, 0, 0);
        }
    }

    // ---- fp32 ||x||^2 partial + bf16 convert (overlaps staging) ----
    float xx = 0.f;
    #pragma unroll
    for (int ks = 0; ks < 2; ++ks)
        #pragma unroll
        for (int u = 0; u < 2; ++u) {
            float4 v = ar[ks][u];
            xx = fmaf(v.x, v.x, fmaf(v.y, v.y, fmaf(v.z, v.z, fmaf(v.w, v.w, xx))));
        }
    bf16x8 a[2];
    #pragma unroll
    for (int ks = 0; ks < 2; ++ks) {
        float4 v0 = ar[ks][0], v1 = ar[ks][1];
        bf16x8 f;
        f[0] = f2bf(v0.x); f[1] = f2bf(v0.y); f[2] = f2bf(v0.z); f[3] = f2bf(v0.w);
        f[4] = f2bf(v1.x); f[5] = f2bf(v1.y); f[6] = f2bf(v1.z); f[7] = f2bf(v1.w);
        a[ks] = f;
    }

    // ---- main loop: 2 passes x 16 col-tiles ----
    float pm[4];
    #pragma unroll
    for (int i = 0; i < 4; ++i) pm[i] = __builtin_bit_cast(float, 0x7F800000u);

    #pragma unroll
    for (int p = 0; p < 2; ++p) {
        if (p) {
            __syncthreads();   // previous pass fully consumed
            char* dst = (char*)lbuf;
            #pragma unroll
            for (int k = 0; k < 8; ++k) {
                const int off = (k * 256 + tid) * 16;
                __builtin_amdgcn_global_load_lds(
                    (const __attribute__((address_space(1))) void*)(wsg + 32768 + off),
                    (__attribute__((address_space(3))) void*)(dst + off), 16, 0, 0);
            }
        }
        // this pass's 16 half-norms for this lane's column class (L1-hit, fp32)
        const float4* hp = (const float4*)(wsg + WS_EE + cb * 128 + p * 64);
        float4 h0 = hp[0], h1 = hp[1], h2 = hp[2], h3 = hp[3];
        __syncthreads();       // staging complete (vmcnt(0) at barrier)

        #pragma unroll
        for (int ctl = 0; ctl < 16; ++ctl) {
            bf16x8 b0 = lbuf[ctl * 128 + lane];
            bf16x8 b1 = lbuf[ctl * 128 + 64 + lane];
            const int ct = p * 16 + ctl;
            const int colv = (ct << 4) | cb;
            const float4 hq = (ctl < 8) ? ((ctl < 4) ? h0 : h1) : ((ctl < 12) ? h2 : h3);
            const float h = (ctl & 3) == 0 ? hq.x : (ctl & 3) == 1 ? hq.y
                          : (ctl & 3) == 2 ? hq.z : hq.w;
            f32x4 acc = {h, h, h, h};        // 0.5||e||^2 - x.e   (B = -e)
            acc = __builtin_amdgcn_mfma_f32_16x16x32_bf16(a[0], b0, acc, 0, 0, 0);
            acc = __builtin_amdgcn_mfma_f32_16x16x32_bf16(a[1], b1, acc, 0, 0, 0);
            #pragma unroll
            for (int j = 0; j < 4; ++j) {
                uint32_t dp = (__builtin_bit_cast(uint32_t, acc[j]) & 0xFFFFFE00u) | (uint32_t)colv;
                pm[j] = fminf(pm[j], __builtin_bit_cast(float, dp));
            }
        }
    }

    // ---- butterfly min over the 16 column-class lanes ----
    #pragma unroll
    for (int m = 1; m < 16; m <<= 1) {
        #pragma unroll
        for (int i = 0; i < 4; ++i)
            pm[i] = fminf(pm[i], __shfl_xor(pm[i], m, 64));
    }
    // post-butterfly: all 16 lanes of group g hold winners of rows rb+g*4+j

    // ---- loss partial: sum_rows( ||x||^2 + 2*unpack(pm_min) ) ----
    float t = xx;
    if (cb == 0) {
        #pragma unroll
        for (int j = 0; j < 4; ++j) {
            float v = __builtin_bit_cast(float, __builtin_bit_cast(uint32_t, pm[j]) & 0xFFFFFE00u);
            t = fmaf(2.f, v, t);
        }
    }
    #pragma unroll
    for (int m = 32; m; m >>= 1) t += __shfl_down(t, m, 64);
    if (lane == 0) red[wid] = t;

    // ---- epilogue: shuffle-free group-parallel gather + store ----
    // group g owns rows rb+g*4+j; its 16 lanes cover the 64-dim row as float4s
    float* ob = out + 1 + (long)rb * 64;
    const int l4 = cb * 4;
    #pragma unroll
    for (int j = 0; j < 4; ++j) {
        const int ix = (int)(__builtin_bit_cast(uint32_t, pm[j]) & 0x1FFu);
        float4 e = *(const float4*)(emb + ix * 64 + l4);
        const int ro = (g * 4 + j) * 64 + l4;
        ob[ro] = e.x; ob[ro + 1] = e.y; ob[ro + 2] = e.z; ob[ro + 3] = e.w;
    }

    __syncthreads();
    if (tid == 0) {
        float* part = (float*)(ws + WS_PART);
        part[bid] = red[0] + red[1] + red[2] + red[3];
    }
}

// ---------------- Kernel 3: deterministic final reduce (1 block) ----------------
__global__ __launch_bounds__(256)
void vq_loss(const float* __restrict__ partials, float* __restrict__ out) {
    __shared__ float red[4];
    const int tid = threadIdx.x;
    float acc = partials[tid] + partials[tid + 256] + partials[tid + 512] + partials[tid + 768];
    #pragma unroll
    for (int m = 32; m; m >>= 1) acc += __shfl_down(acc, m, 64);
    if ((tid & 63) == 0) red[tid >> 6] = acc;
    __syncthreads();
    // loss = 0.25*e_loss + q_loss = 1.25 * mse (forward)
    if (tid == 0) out[0] = 1.25f * (red[0] + red[1] + red[2] + red[3]) / 4194304.0f;
}

extern "C" void kernel_launch(void* const* d_in, const int* in_sizes, int n_in,
                              void* d_out, int out_size, void* d_ws, size_t ws_size,
                              hipStream_t stream) {
    const float* flat = (const float*)d_in[0];   // [65536,64]
    const float* emb  = (const float*)d_in[1];   // [512,64]
    float* out = (float*)d_out;
    char* ws = (char*)d_ws;

    vq_setup<<<16, 256, 0, stream>>>(emb, ws);
    vq_main<<<1024, 256, 0, stream>>>(flat, emb, ws, out);
    vq_loss<<<1, 256, 0, stream>>>((const float*)(ws + WS_PART), out);
}